// Round 7
// baseline (7189.568 us; speedup 1.0000x reference)
//
#include <hip/hip_runtime.h>
#include <stdint.h>

// Persistent-LSTM, round 7: flag-gated XCD-local h exchange.
//  - 256 WGs x 128 threads (2 waves), 1 WG/CU (105 KB LDS forces this).
//  - Slab g = bid&7 (batch rows 8g..8g+7, XCD-co-resident by round-robin
//    dispatch); m = bid>>3 owns u-cols 16m..16m+15 (64 z-cols).
//  - h element = u32 ((t+1)<<16 | bf16(h)), parity double buffer.
//    Producer: store sc0 (ack => XCD-L2 fresh) then sc1 (IF$ fallback copy),
//    s_waitcnt vmcnt(1) (waits ONLY the sc0 ack, not the IF$ round-trip),
//    raw s_barrier, then tid0 dual-stores a per-WG flag = t+1.
//  - Consumer: speculative h load (overlaps x-phase); tag-validate; if stale,
//    poll FLAGS (1 dword/lane: 256 B/wave/retry vs 16 KB data re-reads that
//    saturated the L2 in round 6), then reload data once. Tags stay
//    authoritative -> any visibility surprise is a retry, never corruption.
//  - Escalation: cumulative flag budget (16384) + per-step data-retry cap
//    (64) -> sticky switch to sc1/IF$ loads (round-4-proven path). Kills
//    round-6's 75 ms "borderline visibility" mode (per-step cap never
//    tripped at ~400 retries/step).
//  - 2-buffer WAR safety: flag t+1 implies that WG consumed h_t, so a
//    tag-(t+2) overwrite of parity t requires all readers done with h_t.

#define Tt   1024
#define Ff   256
#define Uu   512
#define G4U  2048
#define NWG  256
#define NTHR 128
#define DTRIES_MAX 64
#define FBUDGET    16384

#define WF_ELEMS (4 * 24 * 64 * 8)                  // 49152 bf16 = 96 KB
#define WF_BYTES (WF_ELEMS * 2)
#define ZB_BYTES (2 * 4 * 16 * 17 * 4)              // 8704 B
#define SMEM_BYTES (WF_BYTES + ZB_BYTES)

typedef short  bf16x8 __attribute__((ext_vector_type(8)));
typedef float  f32x4  __attribute__((ext_vector_type(4)));
typedef int    int4v  __attribute__((ext_vector_type(4)));
typedef unsigned int u32;

__device__ __forceinline__ unsigned short f2bf(float f) {
  u32 u = __builtin_bit_cast(u32, f);
  u += 0x7fffu + ((u >> 16) & 1u);                  // RNE (finite inputs)
  return (unsigned short)(u >> 16);
}
__device__ __forceinline__ u32 umin32(u32 a, u32 b) { return a < b ? a : b; }

// sc0: bypass per-CU L1, serve from the XCD-shared (coherent) L2.
__device__ __forceinline__ int4v load16_l2(const u32* p) {
  int4v r;
  asm volatile("global_load_dwordx4 %0, %1, off sc0"
               : "=v"(r) : "v"(p) : "memory");
  return r;
}
// sc1: agent scope, served at IF$ (escalation fallback).
__device__ __forceinline__ int4v load16_ag(const u32* p) {
  int4v r;
  asm volatile("global_load_dwordx4 %0, %1, off sc1"
               : "=v"(r) : "v"(p) : "memory");
  return r;
}
__device__ __forceinline__ void store4_l2(u32* p, u32 v) {
  asm volatile("global_store_dword %0, %1, off sc0"
               :: "v"(p), "v"(v) : "memory");
}
__device__ __forceinline__ void store4_ag(u32* p, u32 v) {
  asm volatile("global_store_dword %0, %1, off sc1"
               :: "v"(p), "v"(v) : "memory");
}
__device__ __forceinline__ u32 load_flag(int esc, const u32* p) {
  u32 r;
  if (!esc)
    asm volatile("global_load_dword %0, %1, off sc0\n\ts_waitcnt vmcnt(0)"
                 : "=v"(r) : "v"(p) : "memory");
  else
    asm volatile("global_load_dword %0, %1, off sc1\n\ts_waitcnt vmcnt(0)"
                 : "=v"(r) : "v"(p) : "memory");
  return r;
}
__device__ __forceinline__ void loadH(int esc, const u32* hp, int w, int4v* hf) {
  if (!esc) {
    #pragma unroll
    for (int q = 0; q < 8; ++q) {
      hf[2 * q]     = load16_l2(hp + (2 * q + w) * 32);
      hf[2 * q + 1] = load16_l2(hp + (2 * q + w) * 32 + 4);
    }
  } else {
    #pragma unroll
    for (int q = 0; q < 8; ++q) {
      hf[2 * q]     = load16_ag(hp + (2 * q + w) * 32);
      hf[2 * q + 1] = load16_ag(hp + (2 * q + w) * 32 + 4);
    }
  }
}

__device__ __forceinline__ float sigf(float z) {
  return __builtin_amdgcn_rcpf(1.f + __expf(-z));
}
__device__ __forceinline__ float tanh_fast(float v) {
  const float e = __expf(-2.f * fabsf(v));
  const float r = (1.f - e) * __builtin_amdgcn_rcpf(1.f + e);
  return copysignf(r, v);
}

extern "C" __global__ void __launch_bounds__(NTHR, 1)
lstm_persistent(const float* __restrict__ x,
                const float* __restrict__ Wk,
                const float* __restrict__ Rk,
                const float* __restrict__ bias,
                float* __restrict__ out,
                u32* __restrict__ hbuf,             // [2][64][512] tagged u32
                u32* __restrict__ flags)            // [8][32] monotonic
{
  extern __shared__ char smem[];
  unsigned short* wf   = (unsigned short*)smem;            // [nt4][kt24][64][8]
  float*          zbuf = (float*)(smem + WF_BYTES);        // [w][nt][16][17]

  const int bid = blockIdx.x;
  const int tid = threadIdx.x;
  const int w   = tid >> 6;
  const int l   = tid & 63;
  const int g   = bid & 7;         // row slab (XCD-local by dispatch RR)
  const int m   = bid >> 3;        // u-cols 16m..16m+15

  // ---- one-time weight staging into MFMA B-fragment order ----
  for (int i = tid; i < WF_ELEMS; i += NTHR) {
    const int j    = i & 7;
    const int lane = (i >> 3) & 63;
    const int kt   = (i >> 9) % 24;
    const int nt   = (i >> 9) / 24;
    const int k    = kt * 32 + ((lane >> 4) << 3) + j;     // 0..767
    const int zc   = nt * Uu + m * 16 + (lane & 15);       // gate*512 + u
    const float v  = (k < Ff) ? Wk[(size_t)k * G4U + zc]
                              : Rk[(size_t)(k - Ff) * G4U + zc];
    wf[i] = f2bf(v);
  }
  __syncthreads();

  // ---- preload x-part weight fragments (kt = 2q+w; 64 VGPR) ----
  bf16x8 wfx[4][4];
  #pragma unroll
  for (int q = 0; q < 4; ++q)
    #pragma unroll
    for (int nt = 0; nt < 4; ++nt)
      wfx[q][nt] = *(const bf16x8*)(wf + ((nt * 24 + (2 * q + w)) * 64 + l) * 8);

  // ---- combine-role constants: 128 threads = 8 rows x 16 u ----
  const int r_c   = tid >> 4;
  const int uu    = tid & 15;
  const int b_out = g * 8 + r_c;
  const int u_out = m * 16 + uu;
  float breg[4];
  #pragma unroll
  for (int gg = 0; gg < 4; ++gg) breg[gg] = bias[gg * Uu + u_out];
  float creg = 0.f;

  // ---- load-role constants (MFMA A-frag; rows 8..15 alias 0..7) ----
  const int b_ld = g * 8 + (l & 7);
  const int kq   = (l >> 4) * 8;

  int esc = 0;
  int fbudget = FBUDGET;

  for (int t = 0; t < Tt; ++t) {
    // ---- speculative h loads (overlap with x-phase) ----
    const u32* hp = hbuf + ((size_t)(t & 1) * 64 + b_ld) * Uu + kq;
    int4v hf[16];
    loadH(esc, hp, w, hf);

    // ---- x phase: fp32 loads + cvt + 16 MFMAs ----
    f32x4 aX[4] = {{0,0,0,0},{0,0,0,0},{0,0,0,0},{0,0,0,0}};
    const float* xp = x + ((size_t)b_ld * Tt + t) * Ff + kq;
    #pragma unroll
    for (int q = 0; q < 4; ++q) {
      const int kt = 2 * q + w;
      const float4 v0 = *(const float4*)(xp + kt * 32);
      const float4 v1 = *(const float4*)(xp + kt * 32 + 4);
      int r0, r1, r2, r3;
      asm("v_cvt_pk_bf16_f32 %0, %1, %2" : "=v"(r0) : "v"(v0.x), "v"(v0.y));
      asm("v_cvt_pk_bf16_f32 %0, %1, %2" : "=v"(r1) : "v"(v0.z), "v"(v0.w));
      asm("v_cvt_pk_bf16_f32 %0, %1, %2" : "=v"(r2) : "v"(v1.x), "v"(v1.y));
      asm("v_cvt_pk_bf16_f32 %0, %1, %2" : "=v"(r3) : "v"(v1.z), "v"(v1.w));
      const int4v ai = {r0, r1, r2, r3};
      const bf16x8 a = __builtin_bit_cast(bf16x8, ai);
      #pragma unroll
      for (int nt = 0; nt < 4; ++nt)
        aX[nt] = __builtin_amdgcn_mfma_f32_16x16x32_bf16(a, wfx[q][nt], aX[nt], 0, 0, 0);
    }

    // ---- tag-validate; on stale: flag-poll (cheap) then reload once ----
    asm volatile("s_waitcnt vmcnt(0)" ::: "memory");
    __builtin_amdgcn_sched_barrier(0);
    int dtries = 0;
    for (;;) {
      u32 m0 = ~0u, m1 = ~0u, m2 = ~0u, m3 = ~0u;
      #pragma unroll
      for (int q = 0; q < 16; ++q) {
        m0 = umin32(m0, (u32)hf[q][0]);
        m1 = umin32(m1, (u32)hf[q][1]);
        m2 = umin32(m2, (u32)hf[q][2]);
        m3 = umin32(m3, (u32)hf[q][3]);
      }
      const u32 mv = umin32(umin32(m0, m1), umin32(m2, m3));
      if (__all((mv >> 16) == (u32)t)) break;        // all tags fresh
      if (++dtries > DTRIES_MAX) esc = 1;            // sticky fallback
      // flag poll: 1 dword per lane, ~256 B/wave/retry
      const u32* fl = flags + g * 32 + (l & 31);
      for (;;) {
        const u32 fv = load_flag(esc, fl);
        if (__all(fv >= (u32)t)) break;
        if (--fbudget < 0) esc = 1;
        __builtin_amdgcn_s_sleep(1);
      }
      loadH(esc, hp, w, hf);
      asm volatile("s_waitcnt vmcnt(0)" ::: "memory");
      __builtin_amdgcn_sched_barrier(0);
    }

    // ---- h phase: repack + 32 MFMAs on validated data ----
    f32x4 aH[4] = {{0,0,0,0},{0,0,0,0},{0,0,0,0},{0,0,0,0}};
    #pragma unroll
    for (int q = 0; q < 8; ++q) {
      const int kt = 8 + 2 * q + w;
      const u32 w0 = __builtin_amdgcn_perm((u32)hf[2*q][1],   (u32)hf[2*q][0],   0x05040100u);
      const u32 w1 = __builtin_amdgcn_perm((u32)hf[2*q][3],   (u32)hf[2*q][2],   0x05040100u);
      const u32 w2 = __builtin_amdgcn_perm((u32)hf[2*q+1][1], (u32)hf[2*q+1][0], 0x05040100u);
      const u32 w3 = __builtin_amdgcn_perm((u32)hf[2*q+1][3], (u32)hf[2*q+1][2], 0x05040100u);
      const int4v ai = {(int)w0, (int)w1, (int)w2, (int)w3};
      const bf16x8 a = __builtin_bit_cast(bf16x8, ai);
      #pragma unroll
      for (int nt = 0; nt < 4; ++nt) {
        const bf16x8 b = *(const bf16x8*)(wf + ((nt * 24 + kt) * 64 + l) * 8);
        aH[nt] = __builtin_amdgcn_mfma_f32_16x16x32_bf16(a, b, aH[nt], 0, 0, 0);
      }
    }

    // ---- z reduce through zbuf (WAR separation = previous bar C) ----
    {
      const int col = l & 15, rb = (l >> 4) * 4;
      #pragma unroll
      for (int nt = 0; nt < 4; ++nt) {
        #pragma unroll
        for (int i = 0; i < 4; ++i)
          zbuf[((w * 4 + nt) * 16 + rb + i) * 17 + col] = aX[nt][i] + aH[nt][i];
      }
    }
    __syncthreads();                                 // bar B (drains ds_write)

    // ---- gate math; h dual-store; counted drain; barrier; flag ----
    float z[4];
    #pragma unroll
    for (int gg = 0; gg < 4; ++gg)
      z[gg] = zbuf[((0 * 4 + gg) * 16 + r_c) * 17 + uu]
            + zbuf[((1 * 4 + gg) * 16 + r_c) * 17 + uu]
            + breg[gg];
    const float ig = sigf(z[0]);
    const float fg = sigf(z[1]);
    const float og = sigf(z[3]);
    const float cc = fg * creg + ig * z[2];
    creg = cc;
    const float hh = og * cc;
    const u32 hw = ((u32)(t + 1) << 16) | (u32)f2bf(hh);
    u32* hq = hbuf + ((size_t)((t + 1) & 1) * 64 + b_out) * Uu + u_out;
    store4_l2(hq, hw);                               // sc0 FIRST (L2 ack)
    store4_ag(hq, hw);                               // sc1 second (IF$ copy)
    asm volatile("s_waitcnt vmcnt(1)" ::: "memory"); // waits sc0 only
    __builtin_amdgcn_sched_barrier(0);
    __builtin_amdgcn_s_barrier();                    // bar C (raw, no drain)
    __builtin_amdgcn_sched_barrier(0);
    if (tid == 0) {
      u32* fp = flags + g * 32 + m;
      store4_l2(fp, (u32)(t + 1));
      store4_ag(fp, (u32)(t + 1));
    }
    out[((size_t)b_out * Tt + t) * Uu + u_out] = tanh_fast(hh);  // fire&forget
  }
}

extern "C" void kernel_launch(void* const* d_in, const int* in_sizes, int n_in,
                              void* d_out, int out_size, void* d_ws, size_t ws_size,
                              hipStream_t stream) {
  const float* x    = (const float*)d_in[0];
  const float* Wk   = (const float*)d_in[1];
  const float* Rk   = (const float*)d_in[2];
  const float* bias = (const float*)d_in[3];
  float* out = (float*)d_out;
  u32* hbuf  = (u32*)d_ws;
  u32* flags = (u32*)((char*)d_ws + (size_t)2 * 64 * Uu * sizeof(u32));

  // zeroed hbuf == valid tag-0 h_0 = 0 (both parities); flags 0 = "h_0 out".
  hipMemsetAsync(d_ws, 0,
                 (size_t)2 * 64 * Uu * sizeof(u32) + 8 * 32 * sizeof(u32),
                 stream);

  (void)hipFuncSetAttribute((const void*)lstm_persistent,
                            hipFuncAttributeMaxDynamicSharedMemorySize,
                            SMEM_BYTES);

  hipLaunchKernelGGL(lstm_persistent, dim3(NWG), dim3(NTHR), SMEM_BYTES, stream,
                     x, Wk, Rk, bias, out, hbuf, flags);
}

// Round 8
// 4430.215 us; speedup vs baseline: 1.6228x; 1.6228x over previous
//
#include <hip/hip_runtime.h>
#include <stdint.h>

// Persistent-LSTM, round 8: round-4 structure + publish-early producer.
//  - 256 WGs x 128 threads (2 waves). WG (g = bid>>6, m = bid&63) owns
//    batch rows 16g..16g+15 and u-columns 8m..8m+7 (32 z-cols, 2 nt tiles).
//  - One recurrence stream per WG; no cross-WG barriers, no flags, no
//    XCD-topology assumptions (those produced 48-75 ms outlier dispatches).
//  - h element = u32 ((t+1)<<16 | bf16(h)) in a parity double buffer at
//    AGENT scope (sc1): bypasses L1 + per-XCD L2, served at the IF$
//    coherence point. Tags embedded in data are the only synchronization.
//  - PUBLISH-EARLY (the round-8 change): after the h store, the producer
//    drains vmcnt(0) BEFORE issuing its out[] store and its next-step
//    speculative loads. Without this the h store queues behind the same
//    CU's 16 h-probe loads + 8 x loads (every WG is producer AND consumer),
//    adding multiple retry quanta to every consumer of this slab.
//  - 2-buffer WAR safety: a tag-(t+2) write needs full h_{t+1}, which needs
//    every WG to have consumed h_t -> no overwrite race. Zeroed hbuf is the
//    valid tag-0 h_0 = 0 state.

#define Tt   1024
#define Uu   512
#define G4U  2048
#define NWG  256
#define NTHR 128

#define WF_ELEMS (2 * 24 * 64 * 8)                 // 24576 bf16 = 48 KB
#define WF_BYTES (WF_ELEMS * 2)
#define ZB_PLANE (16 * 17)                         // padded 16x16 f32 tile
#define SMEM_BYTES (WF_BYTES + 4 * ZB_PLANE * 4)   // 48 KB + 4352 B

typedef short  bf16x8 __attribute__((ext_vector_type(8)));
typedef float  f32x4  __attribute__((ext_vector_type(4)));
typedef int    int4v  __attribute__((ext_vector_type(4)));
typedef unsigned int u32;

__device__ __forceinline__ unsigned short f2bf(float f) {
  u32 u = __builtin_bit_cast(u32, f);
  u += 0x7fffu + ((u >> 16) & 1u);                 // RNE (finite inputs)
  return (unsigned short)(u >> 16);
}
__device__ __forceinline__ u32 umin32(u32 a, u32 b) { return a < b ? a : b; }

// Agent scope: bypass L1 and the non-coherent per-XCD L2; serve at IF$.
__device__ __forceinline__ int4v load16_ag(const u32* p) {
  int4v r;
  asm volatile("global_load_dwordx4 %0, %1, off sc1"
               : "=v"(r) : "v"(p) : "memory");
  return r;
}
__device__ __forceinline__ void store4_ag(u32* p, u32 v) {
  asm volatile("global_store_dword %0, %1, off sc1"
               :: "v"(p), "v"(v) : "memory");
}

__device__ __forceinline__ float sigf(float z) {
  return __builtin_amdgcn_rcpf(1.f + __expf(-z));
}
__device__ __forceinline__ float tanh_fast(float v) {
  const float e = __expf(-2.f * fabsf(v));
  const float r = (1.f - e) * __builtin_amdgcn_rcpf(1.f + e);
  return copysignf(r, v);
}

extern "C" __global__ void __launch_bounds__(NTHR, 1)
lstm_persistent(const float* __restrict__ x,
                const float* __restrict__ Wk,
                const float* __restrict__ Rk,
                const float* __restrict__ bias,
                float* __restrict__ out,
                u32* __restrict__ hbuf)            // [2][64][512] tagged u32
{
  extern __shared__ char smem[];
  unsigned short* wf   = (unsigned short*)smem;            // [nt][kt][lane][8]
  float*          zbuf = (float*)(smem + WF_BYTES);        // [w][nt][16][17]

  const int bid = blockIdx.x;
  const int tid = threadIdx.x;
  const int w   = tid >> 6;
  const int l   = tid & 63;
  const int g   = bid >> 6;        // row group: batch rows 16g..16g+15
  const int m   = bid & 63;        // u-cols 8m..8m+7

  // ---- one-time weight staging into MFMA B-fragment order ----
  for (int i = tid; i < WF_ELEMS; i += NTHR) {
    const int j    = i & 7;
    const int lane = (i >> 3) & 63;
    const int kt   = (i >> 9) % 24;
    const int nt   = (i >> 9) / 24;
    const int k    = kt * 32 + ((lane >> 4) << 3) + j;     // 0..767
    const int n    = nt * 16 + (lane & 15);                // 0..31
    const int zc   = (n >> 3) * Uu + m * 8 + (n & 7);      // gate*512 + u
    const float v  = (k < 256) ? Wk[(size_t)k * G4U + zc]
                               : Rk[(size_t)(k - 256) * G4U + zc];
    wf[i] = f2bf(v);
  }
  __syncthreads();

  // ---- preload x-part weight fragments (kt = 2q+w, q=0..3) ----
  bf16x8 wfx[4][2];
  #pragma unroll
  for (int q = 0; q < 4; ++q)
    #pragma unroll
    for (int nt = 0; nt < 2; ++nt)
      wfx[q][nt] = *(const bf16x8*)(wf + (((nt * 24) + (2 * q + w)) * 64 + l) * 8);

  // ---- combine-role constants (one (row,u) pair per thread) ----
  const int row_c = tid >> 3;                  // 0..15
  const int uu    = tid & 7;
  const int b_out = g * 16 + row_c;
  const int u_out = m * 8 + uu;
  float breg[4];
  #pragma unroll
  for (int gg = 0; gg < 4; ++gg) breg[gg] = bias[gg * Uu + u_out];
  float creg = 0.f;

  // ---- load-role constants (lane-level, MFMA A-fragment) ----
  const int b_ld = g * 16 + (l & 15);
  const int kq   = (l >> 4) * 8;

  for (int t = 0; t < Tt; ++t) {
    // ---- issue agent-scope tagged-h loads first (latency hides under x) ----
    const u32* hp = hbuf + ((size_t)(t & 1) * 64 + b_ld) * Uu + kq;
    int4v hf[16];
    #pragma unroll
    for (int q = 0; q < 8; ++q) {
      hf[2 * q]     = load16_ag(hp + (2 * q + w) * 32);
      hf[2 * q + 1] = load16_ag(hp + (2 * q + w) * 32 + 4);
    }

    // ---- x phase: fp32 loads + cvt + 8 MFMAs (kt = 2q+w) ----
    f32x4 aX0 = {0.f, 0.f, 0.f, 0.f};
    f32x4 aX1 = {0.f, 0.f, 0.f, 0.f};
    const float* xp = x + ((size_t)b_ld * Tt + t) * 256 + kq;
    #pragma unroll
    for (int q = 0; q < 4; ++q) {
      const int kt = 2 * q + w;
      const float4 v0 = *(const float4*)(xp + kt * 32);
      const float4 v1 = *(const float4*)(xp + kt * 32 + 4);
      int r0, r1, r2, r3;
      asm("v_cvt_pk_bf16_f32 %0, %1, %2" : "=v"(r0) : "v"(v0.x), "v"(v0.y));
      asm("v_cvt_pk_bf16_f32 %0, %1, %2" : "=v"(r1) : "v"(v0.z), "v"(v0.w));
      asm("v_cvt_pk_bf16_f32 %0, %1, %2" : "=v"(r2) : "v"(v1.x), "v"(v1.y));
      asm("v_cvt_pk_bf16_f32 %0, %1, %2" : "=v"(r3) : "v"(v1.z), "v"(v1.w));
      const int4v ai = {r0, r1, r2, r3};
      const bf16x8 a = __builtin_bit_cast(bf16x8, ai);
      aX0 = __builtin_amdgcn_mfma_f32_16x16x32_bf16(a, wfx[q][0], aX0, 0, 0, 0);
      aX1 = __builtin_amdgcn_mfma_f32_16x16x32_bf16(a, wfx[q][1], aX1, 0, 0, 0);
    }

    // ---- h poll: validate embedded tags only (small retry quantum) ----
    for (;;) {
      asm volatile("s_waitcnt vmcnt(0)" ::: "memory");
      __builtin_amdgcn_sched_barrier(0);
      u32 m0 = ~0u, m1 = ~0u, m2 = ~0u, m3 = ~0u;
      #pragma unroll
      for (int q = 0; q < 16; ++q) {
        m0 = umin32(m0, (u32)hf[q][0]);
        m1 = umin32(m1, (u32)hf[q][1]);
        m2 = umin32(m2, (u32)hf[q][2]);
        m3 = umin32(m3, (u32)hf[q][3]);
      }
      const u32 mv = umin32(umin32(m0, m1), umin32(m2, m3));
      if (__all((mv >> 16) == (u32)t)) break;      // all tags fresh
      __builtin_amdgcn_s_sleep(1);
      #pragma unroll
      for (int q = 0; q < 8; ++q) {                // re-issue stale loads
        hf[2 * q]     = load16_ag(hp + (2 * q + w) * 32);
        hf[2 * q + 1] = load16_ag(hp + (2 * q + w) * 32 + 4);
      }
    }

    // ---- h phase: repack + 16 MFMAs, once, on validated data ----
    f32x4 aH0 = {0.f, 0.f, 0.f, 0.f};
    f32x4 aH1 = {0.f, 0.f, 0.f, 0.f};
    #pragma unroll
    for (int q = 0; q < 8; ++q) {
      const int kt = 8 + 2 * q + w;
      const u32 w0 = __builtin_amdgcn_perm((u32)hf[2*q][1],   (u32)hf[2*q][0],   0x05040100u);
      const u32 w1 = __builtin_amdgcn_perm((u32)hf[2*q][3],   (u32)hf[2*q][2],   0x05040100u);
      const u32 w2 = __builtin_amdgcn_perm((u32)hf[2*q+1][1], (u32)hf[2*q+1][0], 0x05040100u);
      const u32 w3 = __builtin_amdgcn_perm((u32)hf[2*q+1][3], (u32)hf[2*q+1][2], 0x05040100u);
      const int4v ai = {(int)w0, (int)w1, (int)w2, (int)w3};
      const bf16x8 a = __builtin_bit_cast(bf16x8, ai);
      const bf16x8 b0 = *(const bf16x8*)(wf + ((0 * 24 + kt) * 64 + l) * 8);
      const bf16x8 b1 = *(const bf16x8*)(wf + ((1 * 24 + kt) * 64 + l) * 8);
      aH0 = __builtin_amdgcn_mfma_f32_16x16x32_bf16(a, b0, aH0, 0, 0, 0);
      aH1 = __builtin_amdgcn_mfma_f32_16x16x32_bf16(a, b1, aH1, 0, 0, 0);
    }

    const f32x4 z0 = aX0 + aH0;
    const f32x4 z1 = aX1 + aH1;

    // ---- cross-wave z reduce through zbuf ----
    __syncthreads();                             // WAR vs previous combine
    {
      float* zb = zbuf + ((w * 2 + 0) * 16 + (l >> 4) * 4) * 17 + (l & 15);
      #pragma unroll
      for (int r = 0; r < 4; ++r) {
        zb[r * 17]           = z0[r];
        zb[r * 17 + 16 * 17] = z1[r];            // nt=1 plane
      }
    }
    __syncthreads();

    // ---- gate math (fp32), cell update ----
    float z[4];
    #pragma unroll
    for (int gg = 0; gg < 4; ++gg) {
      const int n  = gg * 8 + uu;
      const int nt = n >> 4, nc = n & 15;
      z[gg] = zbuf[((0 + nt) * 16 + row_c) * 17 + nc]
            + zbuf[((2 + nt) * 16 + row_c) * 17 + nc]
            + breg[gg];
    }
    const float ig = sigf(z[0]);
    const float fg = sigf(z[1]);
    const float og = sigf(z[3]);
    const float cc = fg * creg + ig * z[2];
    creg = cc;
    const float hh = og * cc;

    // ---- PUBLISH-EARLY: h store + full drain BEFORE anything else ----
    const u32 hw = ((u32)(t + 1) << 16) | (u32)f2bf(hh);
    store4_ag(hbuf + ((size_t)((t + 1) & 1) * 64 + b_out) * Uu + u_out, hw);
    asm volatile("s_waitcnt vmcnt(0)" ::: "memory");   // h at IF$ NOW
    __builtin_amdgcn_sched_barrier(0);

    // out store is fire-and-forget, off the recurrence critical path
    out[((size_t)b_out * Tt + t) * Uu + u_out] = tanh_fast(hh);
  }
}

extern "C" void kernel_launch(void* const* d_in, const int* in_sizes, int n_in,
                              void* d_out, int out_size, void* d_ws, size_t ws_size,
                              hipStream_t stream) {
  const float* x    = (const float*)d_in[0];
  const float* Wk   = (const float*)d_in[1];
  const float* Rk   = (const float*)d_in[2];
  const float* bias = (const float*)d_in[3];
  float* out = (float*)d_out;
  u32* hbuf = (u32*)d_ws;

  // zeroed hbuf == valid tag-0 h_0 = 0 for both parities.
  hipMemsetAsync(d_ws, 0, (size_t)2 * 64 * Uu * sizeof(u32), stream);

  (void)hipFuncSetAttribute((const void*)lstm_persistent,
                            hipFuncAttributeMaxDynamicSharedMemorySize,
                            SMEM_BYTES);

  hipLaunchKernelGGL(lstm_persistent, dim3(NWG), dim3(NTHR), SMEM_BYTES, stream,
                     x, Wk, Rk, bias, out, hbuf);
}

// Round 9
// 4322.646 us; speedup vs baseline: 1.6632x; 1.0249x over previous
//
#include <hip/hip_runtime.h>
#include <stdint.h>

// Persistent-LSTM, round 9: r8 + cache-residency fixes (no protocol changes).
//  - 256 WGs x 128 threads (2 waves). g = bid&3 (batch rows 16g..16g+15),
//    m = bid>>2 (u-cols 8m..8m+7). Under round-robin dispatch group g's
//    64 WGs land on XCDs {g, g+4} only -> x-rows cached by 2 L2s instead of
//    8 (FETCH amplification 8x -> 2x). Locality-only assumption: wrong
//    mapping degrades speed, never correctness (tags remain the only sync).
//  - out[] stores are NON-TEMPORAL: 256 MB of write-once streaming data no
//    longer churns IF$ allocation, keeping the 512 KB hbuf IF$-resident so
//    h publish + poll retries run at IF$ latency, not HBM latency.
//    (r8 evidence: 1.12 GB FETCH_SIZE vs 67 MB of actual input = x-amp +
//    hbuf IF$ misses.)
//  - Everything else = r8: tagged u32 h ((t+1)<<16 | bf16) in parity double
//    buffer at agent scope (sc1), tag-validate poll, publish-early drain,
//    weights in LDS MFMA B-frag order, K-parity wave split + zbuf reduce.

#define Tt   1024
#define Uu   512
#define G4U  2048
#define NWG  256
#define NTHR 128

#define WF_ELEMS (2 * 24 * 64 * 8)                 // 24576 bf16 = 48 KB
#define WF_BYTES (WF_ELEMS * 2)
#define ZB_PLANE (16 * 17)                         // padded 16x16 f32 tile
#define SMEM_BYTES (WF_BYTES + 4 * ZB_PLANE * 4)   // 48 KB + 4352 B

typedef short  bf16x8 __attribute__((ext_vector_type(8)));
typedef float  f32x4  __attribute__((ext_vector_type(4)));
typedef int    int4v  __attribute__((ext_vector_type(4)));
typedef unsigned int u32;

__device__ __forceinline__ unsigned short f2bf(float f) {
  u32 u = __builtin_bit_cast(u32, f);
  u += 0x7fffu + ((u >> 16) & 1u);                 // RNE (finite inputs)
  return (unsigned short)(u >> 16);
}
__device__ __forceinline__ u32 umin32(u32 a, u32 b) { return a < b ? a : b; }

// Agent scope: bypass L1 and the non-coherent per-XCD L2; serve at IF$.
__device__ __forceinline__ int4v load16_ag(const u32* p) {
  int4v r;
  asm volatile("global_load_dwordx4 %0, %1, off sc1"
               : "=v"(r) : "v"(p) : "memory");
  return r;
}
__device__ __forceinline__ void store4_ag(u32* p, u32 v) {
  asm volatile("global_store_dword %0, %1, off sc1"
               :: "v"(p), "v"(v) : "memory");
}

__device__ __forceinline__ float sigf(float z) {
  return __builtin_amdgcn_rcpf(1.f + __expf(-z));
}
__device__ __forceinline__ float tanh_fast(float v) {
  const float e = __expf(-2.f * fabsf(v));
  const float r = (1.f - e) * __builtin_amdgcn_rcpf(1.f + e);
  return copysignf(r, v);
}

extern "C" __global__ void __launch_bounds__(NTHR, 1)
lstm_persistent(const float* __restrict__ x,
                const float* __restrict__ Wk,
                const float* __restrict__ Rk,
                const float* __restrict__ bias,
                float* __restrict__ out,
                u32* __restrict__ hbuf)            // [2][64][512] tagged u32
{
  extern __shared__ char smem[];
  unsigned short* wf   = (unsigned short*)smem;            // [nt][kt][lane][8]
  float*          zbuf = (float*)(smem + WF_BYTES);        // [w][nt][16][17]

  const int bid = blockIdx.x;
  const int tid = threadIdx.x;
  const int w   = tid >> 6;
  const int l   = tid & 63;
  const int g   = bid & 3;         // row group on XCD pair {g, g+4}
  const int m   = bid >> 2;        // u-cols 8m..8m+7

  // ---- one-time weight staging into MFMA B-fragment order ----
  for (int i = tid; i < WF_ELEMS; i += NTHR) {
    const int j    = i & 7;
    const int lane = (i >> 3) & 63;
    const int kt   = (i >> 9) % 24;
    const int nt   = (i >> 9) / 24;
    const int k    = kt * 32 + ((lane >> 4) << 3) + j;     // 0..767
    const int n    = nt * 16 + (lane & 15);                // 0..31
    const int zc   = (n >> 3) * Uu + m * 8 + (n & 7);      // gate*512 + u
    const float v  = (k < 256) ? Wk[(size_t)k * G4U + zc]
                               : Rk[(size_t)(k - 256) * G4U + zc];
    wf[i] = f2bf(v);
  }
  __syncthreads();

  // ---- preload x-part weight fragments (kt = 2q+w, q=0..3) ----
  bf16x8 wfx[4][2];
  #pragma unroll
  for (int q = 0; q < 4; ++q)
    #pragma unroll
    for (int nt = 0; nt < 2; ++nt)
      wfx[q][nt] = *(const bf16x8*)(wf + (((nt * 24) + (2 * q + w)) * 64 + l) * 8);

  // ---- combine-role constants (one (row,u) pair per thread) ----
  const int row_c = tid >> 3;                  // 0..15
  const int uu    = tid & 7;
  const int b_out = g * 16 + row_c;
  const int u_out = m * 8 + uu;
  float breg[4];
  #pragma unroll
  for (int gg = 0; gg < 4; ++gg) breg[gg] = bias[gg * Uu + u_out];
  float creg = 0.f;

  // ---- load-role constants (lane-level, MFMA A-fragment) ----
  const int b_ld = g * 16 + (l & 15);
  const int kq   = (l >> 4) * 8;

  for (int t = 0; t < Tt; ++t) {
    // ---- issue agent-scope tagged-h loads first (latency hides under x) ----
    const u32* hp = hbuf + ((size_t)(t & 1) * 64 + b_ld) * Uu + kq;
    int4v hf[16];
    #pragma unroll
    for (int q = 0; q < 8; ++q) {
      hf[2 * q]     = load16_ag(hp + (2 * q + w) * 32);
      hf[2 * q + 1] = load16_ag(hp + (2 * q + w) * 32 + 4);
    }

    // ---- x phase: fp32 loads + cvt + 8 MFMAs (kt = 2q+w) ----
    f32x4 aX0 = {0.f, 0.f, 0.f, 0.f};
    f32x4 aX1 = {0.f, 0.f, 0.f, 0.f};
    const float* xp = x + ((size_t)b_ld * Tt + t) * 256 + kq;
    #pragma unroll
    for (int q = 0; q < 4; ++q) {
      const int kt = 2 * q + w;
      const float4 v0 = *(const float4*)(xp + kt * 32);
      const float4 v1 = *(const float4*)(xp + kt * 32 + 4);
      int r0, r1, r2, r3;
      asm("v_cvt_pk_bf16_f32 %0, %1, %2" : "=v"(r0) : "v"(v0.x), "v"(v0.y));
      asm("v_cvt_pk_bf16_f32 %0, %1, %2" : "=v"(r1) : "v"(v0.z), "v"(v0.w));
      asm("v_cvt_pk_bf16_f32 %0, %1, %2" : "=v"(r2) : "v"(v1.x), "v"(v1.y));
      asm("v_cvt_pk_bf16_f32 %0, %1, %2" : "=v"(r3) : "v"(v1.z), "v"(v1.w));
      const int4v ai = {r0, r1, r2, r3};
      const bf16x8 a = __builtin_bit_cast(bf16x8, ai);
      aX0 = __builtin_amdgcn_mfma_f32_16x16x32_bf16(a, wfx[q][0], aX0, 0, 0, 0);
      aX1 = __builtin_amdgcn_mfma_f32_16x16x32_bf16(a, wfx[q][1], aX1, 0, 0, 0);
    }

    // ---- h poll: validate embedded tags only (small retry quantum) ----
    for (;;) {
      asm volatile("s_waitcnt vmcnt(0)" ::: "memory");
      __builtin_amdgcn_sched_barrier(0);
      u32 m0 = ~0u, m1 = ~0u, m2 = ~0u, m3 = ~0u;
      #pragma unroll
      for (int q = 0; q < 16; ++q) {
        m0 = umin32(m0, (u32)hf[q][0]);
        m1 = umin32(m1, (u32)hf[q][1]);
        m2 = umin32(m2, (u32)hf[q][2]);
        m3 = umin32(m3, (u32)hf[q][3]);
      }
      const u32 mv = umin32(umin32(m0, m1), umin32(m2, m3));
      if (__all((mv >> 16) == (u32)t)) break;      // all tags fresh
      __builtin_amdgcn_s_sleep(1);
      #pragma unroll
      for (int q = 0; q < 8; ++q) {                // re-issue stale loads
        hf[2 * q]     = load16_ag(hp + (2 * q + w) * 32);
        hf[2 * q + 1] = load16_ag(hp + (2 * q + w) * 32 + 4);
      }
    }

    // ---- h phase: repack + 16 MFMAs, once, on validated data ----
    f32x4 aH0 = {0.f, 0.f, 0.f, 0.f};
    f32x4 aH1 = {0.f, 0.f, 0.f, 0.f};
    #pragma unroll
    for (int q = 0; q < 8; ++q) {
      const int kt = 8 + 2 * q + w;
      const u32 w0 = __builtin_amdgcn_perm((u32)hf[2*q][1],   (u32)hf[2*q][0],   0x05040100u);
      const u32 w1 = __builtin_amdgcn_perm((u32)hf[2*q][3],   (u32)hf[2*q][2],   0x05040100u);
      const u32 w2 = __builtin_amdgcn_perm((u32)hf[2*q+1][1], (u32)hf[2*q+1][0], 0x05040100u);
      const u32 w3 = __builtin_amdgcn_perm((u32)hf[2*q+1][3], (u32)hf[2*q+1][2], 0x05040100u);
      const int4v ai = {(int)w0, (int)w1, (int)w2, (int)w3};
      const bf16x8 a = __builtin_bit_cast(bf16x8, ai);
      const bf16x8 b0 = *(const bf16x8*)(wf + ((0 * 24 + kt) * 64 + l) * 8);
      const bf16x8 b1 = *(const bf16x8*)(wf + ((1 * 24 + kt) * 64 + l) * 8);
      aH0 = __builtin_amdgcn_mfma_f32_16x16x32_bf16(a, b0, aH0, 0, 0, 0);
      aH1 = __builtin_amdgcn_mfma_f32_16x16x32_bf16(a, b1, aH1, 0, 0, 0);
    }

    const f32x4 z0 = aX0 + aH0;
    const f32x4 z1 = aX1 + aH1;

    // ---- cross-wave z reduce through zbuf ----
    __syncthreads();                             // WAR vs previous combine
    {
      float* zb = zbuf + ((w * 2 + 0) * 16 + (l >> 4) * 4) * 17 + (l & 15);
      #pragma unroll
      for (int r = 0; r < 4; ++r) {
        zb[r * 17]           = z0[r];
        zb[r * 17 + 16 * 17] = z1[r];            // nt=1 plane
      }
    }
    __syncthreads();

    // ---- gate math (fp32), cell update ----
    float z[4];
    #pragma unroll
    for (int gg = 0; gg < 4; ++gg) {
      const int n  = gg * 8 + uu;
      const int nt = n >> 4, nc = n & 15;
      z[gg] = zbuf[((0 + nt) * 16 + row_c) * 17 + nc]
            + zbuf[((2 + nt) * 16 + row_c) * 17 + nc]
            + breg[gg];
    }
    const float ig = sigf(z[0]);
    const float fg = sigf(z[1]);
    const float og = sigf(z[3]);
    const float cc = fg * creg + ig * z[2];
    creg = cc;
    const float hh = og * cc;

    // ---- PUBLISH-EARLY: h store + full drain BEFORE anything else ----
    const u32 hw = ((u32)(t + 1) << 16) | (u32)f2bf(hh);
    store4_ag(hbuf + ((size_t)((t + 1) & 1) * 64 + b_out) * Uu + u_out, hw);
    asm volatile("s_waitcnt vmcnt(0)" ::: "memory");   // h at IF$ NOW
    __builtin_amdgcn_sched_barrier(0);

    // out store: non-temporal fire-and-forget -- 256 MB of streaming writes
    // must not churn IF$ allocation (keeps hbuf resident).
    __builtin_nontemporal_store(tanh_fast(hh),
                                &out[((size_t)b_out * Tt + t) * Uu + u_out]);
  }
}

extern "C" void kernel_launch(void* const* d_in, const int* in_sizes, int n_in,
                              void* d_out, int out_size, void* d_ws, size_t ws_size,
                              hipStream_t stream) {
  const float* x    = (const float*)d_in[0];
  const float* Wk   = (const float*)d_in[1];
  const float* Rk   = (const float*)d_in[2];
  const float* bias = (const float*)d_in[3];
  float* out = (float*)d_out;
  u32* hbuf = (u32*)d_ws;

  // zeroed hbuf == valid tag-0 h_0 = 0 for both parities.
  hipMemsetAsync(d_ws, 0, (size_t)2 * 64 * Uu * sizeof(u32), stream);

  (void)hipFuncSetAttribute((const void*)lstm_persistent,
                            hipFuncAttributeMaxDynamicSharedMemorySize,
                            SMEM_BYTES);

  hipLaunchKernelGGL(lstm_persistent, dim3(NWG), dim3(NTHR), SMEM_BYTES, stream,
                     x, Wk, Rk, bias, out, hbuf);
}

// Round 10
// 3803.889 us; speedup vs baseline: 1.8901x; 1.1364x over previous
//
#include <hip/hip_runtime.h>
#include <stdint.h>

// Persistent-LSTM, round 10: release/acquire h exchange (bf16 data + per-WG
// tags), replacing per-word tag validation.
//  - 256 WGs x 128 threads (2 waves). g = bid&3 (batch rows 16g..16g+15,
//    XCD-pair locality), m = bid>>2 (u-cols 8m..8m+7, 32 z-cols, 2 nt tiles).
//  - hbuf: PLAIN bf16 [2][64][512] parity double buffer. Halves h bytes and
//    makes the MFMA A-fragment a contiguous 16B load (no perm repack).
//  - tags[4][64]: producer release = {store h sc1} -> vmcnt(0) -> s_barrier
//    -> tid0 stores tag=t+1 sc1 (pattern functionally proven in r7).
//    Consumer acquire = poll 64 tags (1 dword/lane, 256 B/wave/retry -- a
//    64x poll-bandwidth cut vs re-reading the 16 KB stripe) then issue the
//    data load strictly after the tag pass (volatile-asm program order +
//    in-order VMEM issue). All exchange ops at agent scope (sc1 / IF$).
//  - 2-buffer WAR safety: all tags >= t+1 => every WG completed its h_t data
//    loads (each WG drains vmcnt(0) on data before publishing) => parity
//    overwrite at t+2 races nothing.
//  - Keeps r9 wins: XCD-pair group mapping, nontemporal out stores,
//    publish-early producer drain.

#define Tt   1024
#define Uu   512
#define G4U  2048
#define NWG  256
#define NTHR 128

#define WF_ELEMS (2 * 24 * 64 * 8)                 // 24576 bf16 = 48 KB
#define WF_BYTES (WF_ELEMS * 2)
#define ZB_PLANE (16 * 17)                         // padded 16x16 f32 tile
#define SMEM_BYTES (WF_BYTES + 4 * ZB_PLANE * 4)   // 48 KB + 4352 B

typedef short  bf16x8 __attribute__((ext_vector_type(8)));
typedef float  f32x4  __attribute__((ext_vector_type(4)));
typedef int    int4v  __attribute__((ext_vector_type(4)));
typedef unsigned int u32;

__device__ __forceinline__ unsigned short f2bf(float f) {
  u32 u = __builtin_bit_cast(u32, f);
  u += 0x7fffu + ((u >> 16) & 1u);                 // RNE (finite inputs)
  return (unsigned short)(u >> 16);
}

// Agent scope (sc1): bypass L1 + non-coherent per-XCD L2; serve at IF$.
__device__ __forceinline__ int4v load16_ag(const unsigned short* p) {
  int4v r;
  asm volatile("global_load_dwordx4 %0, %1, off sc1"
               : "=v"(r) : "v"(p) : "memory");
  return r;
}
__device__ __forceinline__ void store2_ag(unsigned short* p, unsigned short v) {
  asm volatile("global_store_short %0, %1, off sc1"
               :: "v"(p), "v"((u32)v) : "memory");
}
__device__ __forceinline__ void store4_ag(u32* p, u32 v) {
  asm volatile("global_store_dword %0, %1, off sc1"
               :: "v"(p), "v"(v) : "memory");
}
__device__ __forceinline__ u32 load_tag_wait(const u32* p) {
  u32 r;
  asm volatile("global_load_dword %0, %1, off sc1\n\ts_waitcnt vmcnt(0)"
               : "=v"(r) : "v"(p) : "memory");
  return r;
}

__device__ __forceinline__ float sigf(float z) {
  return __builtin_amdgcn_rcpf(1.f + __expf(-z));
}
__device__ __forceinline__ float tanh_fast(float v) {
  const float e = __expf(-2.f * fabsf(v));
  const float r = (1.f - e) * __builtin_amdgcn_rcpf(1.f + e);
  return copysignf(r, v);
}

extern "C" __global__ void __launch_bounds__(NTHR, 1)
lstm_persistent(const float* __restrict__ x,
                const float* __restrict__ Wk,
                const float* __restrict__ Rk,
                const float* __restrict__ bias,
                float* __restrict__ out,
                unsigned short* __restrict__ hbuf,  // [2][64][512] bf16
                u32* __restrict__ tags)             // [4][64] monotonic
{
  extern __shared__ char smem[];
  unsigned short* wf   = (unsigned short*)smem;            // [nt][kt][lane][8]
  float*          zbuf = (float*)(smem + WF_BYTES);        // [w][nt][16][17]

  const int bid = blockIdx.x;
  const int tid = threadIdx.x;
  const int w   = tid >> 6;
  const int l   = tid & 63;
  const int g   = bid & 3;         // row group on XCD pair {g, g+4}
  const int m   = bid >> 2;        // u-cols 8m..8m+7

  // ---- one-time weight staging into MFMA B-fragment order ----
  for (int i = tid; i < WF_ELEMS; i += NTHR) {
    const int j    = i & 7;
    const int lane = (i >> 3) & 63;
    const int kt   = (i >> 9) % 24;
    const int nt   = (i >> 9) / 24;
    const int k    = kt * 32 + ((lane >> 4) << 3) + j;     // 0..767
    const int n    = nt * 16 + (lane & 15);                // 0..31
    const int zc   = (n >> 3) * Uu + m * 8 + (n & 7);      // gate*512 + u
    const float v  = (k < 256) ? Wk[(size_t)k * G4U + zc]
                               : Rk[(size_t)(k - 256) * G4U + zc];
    wf[i] = f2bf(v);
  }
  __syncthreads();

  // ---- preload x-part weight fragments (kt = 2q+w, q=0..3) ----
  bf16x8 wfx[4][2];
  #pragma unroll
  for (int q = 0; q < 4; ++q)
    #pragma unroll
    for (int nt = 0; nt < 2; ++nt)
      wfx[q][nt] = *(const bf16x8*)(wf + (((nt * 24) + (2 * q + w)) * 64 + l) * 8);

  // ---- combine-role constants (one (row,u) pair per thread) ----
  const int row_c = tid >> 3;                  // 0..15
  const int uu    = tid & 7;
  const int b_out = g * 16 + row_c;
  const int u_out = m * 8 + uu;
  float breg[4];
  #pragma unroll
  for (int gg = 0; gg < 4; ++gg) breg[gg] = bias[gg * Uu + u_out];
  float creg = 0.f;

  // ---- load-role constants (lane-level, MFMA A-fragment) ----
  const int b_ld = g * 16 + (l & 15);
  const int kq   = (l >> 4) * 8;
  const u32* tagp = tags + g * 64 + l;          // one producer tag per lane

  for (int t = 0; t < Tt; ++t) {
    // ---- issue the first tag probe early (overlaps the x phase) ----
    u32 tv;
    asm volatile("global_load_dword %0, %1, off sc1"
                 : "=v"(tv) : "v"(tagp) : "memory");

    // ---- x phase: fp32 loads + cvt + 8 MFMAs (kt = 2q+w) ----
    f32x4 aX0 = {0.f, 0.f, 0.f, 0.f};
    f32x4 aX1 = {0.f, 0.f, 0.f, 0.f};
    const float* xp = x + ((size_t)b_ld * Tt + t) * 256 + kq;
    #pragma unroll
    for (int q = 0; q < 4; ++q) {
      const int kt = 2 * q + w;
      const float4 v0 = *(const float4*)(xp + kt * 32);
      const float4 v1 = *(const float4*)(xp + kt * 32 + 4);
      int r0, r1, r2, r3;
      asm("v_cvt_pk_bf16_f32 %0, %1, %2" : "=v"(r0) : "v"(v0.x), "v"(v0.y));
      asm("v_cvt_pk_bf16_f32 %0, %1, %2" : "=v"(r1) : "v"(v0.z), "v"(v0.w));
      asm("v_cvt_pk_bf16_f32 %0, %1, %2" : "=v"(r2) : "v"(v1.x), "v"(v1.y));
      asm("v_cvt_pk_bf16_f32 %0, %1, %2" : "=v"(r3) : "v"(v1.z), "v"(v1.w));
      const int4v ai = {r0, r1, r2, r3};
      const bf16x8 a = __builtin_bit_cast(bf16x8, ai);
      aX0 = __builtin_amdgcn_mfma_f32_16x16x32_bf16(a, wfx[q][0], aX0, 0, 0, 0);
      aX1 = __builtin_amdgcn_mfma_f32_16x16x32_bf16(a, wfx[q][1], aX1, 0, 0, 0);
    }

    // ---- acquire: poll per-WG tags (256 B/wave/retry) ----
    asm volatile("s_waitcnt vmcnt(0)" ::: "memory");
    __builtin_amdgcn_sched_barrier(0);
    while (!__all(tv >= (u32)t)) {
      __builtin_amdgcn_s_sleep(1);
      tv = load_tag_wait(tagp);
      __builtin_amdgcn_sched_barrier(0);
    }

    // ---- h data loads: issued strictly after tag pass ----
    const unsigned short* hrow =
        hbuf + ((size_t)(t & 1) * 64 + b_ld) * Uu + kq;
    int4v hf[8];
    #pragma unroll
    for (int q = 0; q < 8; ++q)
      hf[q] = load16_ag(hrow + (2 * q + w) * 32);
    asm volatile("s_waitcnt vmcnt(0)" ::: "memory");
    __builtin_amdgcn_sched_barrier(0);

    // ---- h phase: 16 MFMAs, contiguous fragments (no repack) ----
    f32x4 aH0 = {0.f, 0.f, 0.f, 0.f};
    f32x4 aH1 = {0.f, 0.f, 0.f, 0.f};
    #pragma unroll
    for (int q = 0; q < 8; ++q) {
      const int kt = 8 + 2 * q + w;
      const bf16x8 a = __builtin_bit_cast(bf16x8, hf[q]);
      const bf16x8 b0 = *(const bf16x8*)(wf + ((0 * 24 + kt) * 64 + l) * 8);
      const bf16x8 b1 = *(const bf16x8*)(wf + ((1 * 24 + kt) * 64 + l) * 8);
      aH0 = __builtin_amdgcn_mfma_f32_16x16x32_bf16(a, b0, aH0, 0, 0, 0);
      aH1 = __builtin_amdgcn_mfma_f32_16x16x32_bf16(a, b1, aH1, 0, 0, 0);
    }

    const f32x4 z0 = aX0 + aH0;
    const f32x4 z1 = aX1 + aH1;

    // ---- cross-wave z reduce through zbuf ----
    __syncthreads();                             // WAR vs previous combine
    {
      float* zb = zbuf + ((w * 2 + 0) * 16 + (l >> 4) * 4) * 17 + (l & 15);
      #pragma unroll
      for (int r = 0; r < 4; ++r) {
        zb[r * 17]           = z0[r];
        zb[r * 17 + 16 * 17] = z1[r];            // nt=1 plane
      }
    }
    __syncthreads();

    // ---- gate math (fp32), cell update ----
    float z[4];
    #pragma unroll
    for (int gg = 0; gg < 4; ++gg) {
      const int n  = gg * 8 + uu;
      const int nt = n >> 4, nc = n & 15;
      z[gg] = zbuf[((0 + nt) * 16 + row_c) * 17 + nc]
            + zbuf[((2 + nt) * 16 + row_c) * 17 + nc]
            + breg[gg];
    }
    const float ig = sigf(z[0]);
    const float fg = sigf(z[1]);
    const float og = sigf(z[3]);
    const float cc = fg * creg + ig * z[2];
    creg = cc;
    const float hh = og * cc;

    // ---- release: h store -> drain -> barrier -> tag store ----
    store2_ag(hbuf + ((size_t)((t + 1) & 1) * 64 + b_out) * Uu + u_out,
              f2bf(hh));
    asm volatile("s_waitcnt vmcnt(0)" ::: "memory");   // h at IF$ NOW
    __builtin_amdgcn_sched_barrier(0);
    __builtin_amdgcn_s_barrier();                      // all 128 producers drained
    if (tid == 0) store4_ag(tags + g * 64 + m, (u32)(t + 1));

    // out store: non-temporal fire-and-forget, off the critical path
    __builtin_nontemporal_store(tanh_fast(hh),
                                &out[((size_t)b_out * Tt + t) * Uu + u_out]);
  }
}

extern "C" void kernel_launch(void* const* d_in, const int* in_sizes, int n_in,
                              void* d_out, int out_size, void* d_ws, size_t ws_size,
                              hipStream_t stream) {
  const float* x    = (const float*)d_in[0];
  const float* Wk   = (const float*)d_in[1];
  const float* Rk   = (const float*)d_in[2];
  const float* bias = (const float*)d_in[3];
  float* out = (float*)d_out;
  unsigned short* hbuf = (unsigned short*)d_ws;
  u32* tags = (u32*)((char*)d_ws + (size_t)2 * 64 * Uu * sizeof(unsigned short));

  // zeroed hbuf = h_0 = 0 (both parities); tags 0 = "h_0 published".
  hipMemsetAsync(d_ws, 0,
                 (size_t)2 * 64 * Uu * sizeof(unsigned short)
                   + 4 * 64 * sizeof(u32),
                 stream);

  (void)hipFuncSetAttribute((const void*)lstm_persistent,
                            hipFuncAttributeMaxDynamicSharedMemorySize,
                            SMEM_BYTES);

  hipLaunchKernelGGL(lstm_persistent, dim3(NWG), dim3(NTHR), SMEM_BYTES, stream,
                     x, Wk, Rk, bias, out, hbuf, tags);
}

// Round 11
// 3270.932 us; speedup vs baseline: 2.1980x; 1.1629x over previous
//
#include <hip/hip_runtime.h>
#include <stdint.h>

// Persistent-LSTM, round 11: r10 + de-serialized tag polling.
//  - 256 WGs x 128 threads (2 waves). g = bid&3 (batch rows 16g..16g+15,
//    XCD-pair locality), m = bid>>2 (u-cols 8m..8m+7).
//  - hbuf: plain bf16 [2][64][512] parity double buffer (contiguous MFMA
//    A-fragments, no repack).
//  - tags SPREAD one-per-64B-line: tags[4][64][16] u32. r10 packed all 256
//    tags into 4 cache lines; 512 polling waves x same-4-lines = coherence-
//    point slice serialization (~2 us/step of the unexplained gap).
//    Spread tags hash across all IF$ slices -> parallel service.
//  - WAVE-0-ONLY poll + s_barrier hand-off: halves poll transactions; the
//    barrier (+sched_barrier) orders wave 1's data loads after wave 0's tag
//    observation, preserving the r10 acquire proof.
//  - Release: {store h sc1} -> vmcnt(0) -> s_barrier -> tid0 stores tag
//    (t+1) sc1.  2-buffer WAR safety as r10 (tag>=t+1 => that WG completed
//    its h_t loads => parity overwrite at t+2 races nothing).
//  - Keeps r9/r10 wins: XCD-pair mapping, nontemporal out, publish-early.

#define Tt   1024
#define Uu   512
#define G4U  2048
#define NWG  256
#define NTHR 128
#define TAGSTRIDE 16                               // u32s per tag line (64 B)

#define WF_ELEMS (2 * 24 * 64 * 8)                 // 24576 bf16 = 48 KB
#define WF_BYTES (WF_ELEMS * 2)
#define ZB_PLANE (16 * 17)                         // padded 16x16 f32 tile
#define SMEM_BYTES (WF_BYTES + 4 * ZB_PLANE * 4)   // 48 KB + 4352 B

typedef short  bf16x8 __attribute__((ext_vector_type(8)));
typedef float  f32x4  __attribute__((ext_vector_type(4)));
typedef int    int4v  __attribute__((ext_vector_type(4)));
typedef unsigned int u32;

__device__ __forceinline__ unsigned short f2bf(float f) {
  u32 u = __builtin_bit_cast(u32, f);
  u += 0x7fffu + ((u >> 16) & 1u);                 // RNE (finite inputs)
  return (unsigned short)(u >> 16);
}

// Agent scope (sc1): bypass L1 + non-coherent per-XCD L2; serve at IF$.
__device__ __forceinline__ int4v load16_ag(const unsigned short* p) {
  int4v r;
  asm volatile("global_load_dwordx4 %0, %1, off sc1"
               : "=v"(r) : "v"(p) : "memory");
  return r;
}
__device__ __forceinline__ void store2_ag(unsigned short* p, unsigned short v) {
  asm volatile("global_store_short %0, %1, off sc1"
               :: "v"(p), "v"((u32)v) : "memory");
}
__device__ __forceinline__ void store4_ag(u32* p, u32 v) {
  asm volatile("global_store_dword %0, %1, off sc1"
               :: "v"(p), "v"(v) : "memory");
}
__device__ __forceinline__ u32 load_tag_wait(const u32* p) {
  u32 r;
  asm volatile("global_load_dword %0, %1, off sc1\n\ts_waitcnt vmcnt(0)"
               : "=v"(r) : "v"(p) : "memory");
  return r;
}

__device__ __forceinline__ float sigf(float z) {
  return __builtin_amdgcn_rcpf(1.f + __expf(-z));
}
__device__ __forceinline__ float tanh_fast(float v) {
  const float e = __expf(-2.f * fabsf(v));
  const float r = (1.f - e) * __builtin_amdgcn_rcpf(1.f + e);
  return copysignf(r, v);
}

extern "C" __global__ void __launch_bounds__(NTHR, 1)
lstm_persistent(const float* __restrict__ x,
                const float* __restrict__ Wk,
                const float* __restrict__ Rk,
                const float* __restrict__ bias,
                float* __restrict__ out,
                unsigned short* __restrict__ hbuf,  // [2][64][512] bf16
                u32* __restrict__ tags)             // [4][64][16] spread
{
  extern __shared__ char smem[];
  unsigned short* wf   = (unsigned short*)smem;            // [nt][kt][lane][8]
  float*          zbuf = (float*)(smem + WF_BYTES);        // [w][nt][16][17]

  const int bid = blockIdx.x;
  const int tid = threadIdx.x;
  const int w   = tid >> 6;
  const int l   = tid & 63;
  const int g   = bid & 3;         // row group on XCD pair {g, g+4}
  const int m   = bid >> 2;        // u-cols 8m..8m+7

  // ---- one-time weight staging into MFMA B-fragment order ----
  for (int i = tid; i < WF_ELEMS; i += NTHR) {
    const int j    = i & 7;
    const int lane = (i >> 3) & 63;
    const int kt   = (i >> 9) % 24;
    const int nt   = (i >> 9) / 24;
    const int k    = kt * 32 + ((lane >> 4) << 3) + j;     // 0..767
    const int n    = nt * 16 + (lane & 15);                // 0..31
    const int zc   = (n >> 3) * Uu + m * 8 + (n & 7);      // gate*512 + u
    const float v  = (k < 256) ? Wk[(size_t)k * G4U + zc]
                               : Rk[(size_t)(k - 256) * G4U + zc];
    wf[i] = f2bf(v);
  }
  __syncthreads();

  // ---- preload x-part weight fragments (kt = 2q+w, q=0..3) ----
  bf16x8 wfx[4][2];
  #pragma unroll
  for (int q = 0; q < 4; ++q)
    #pragma unroll
    for (int nt = 0; nt < 2; ++nt)
      wfx[q][nt] = *(const bf16x8*)(wf + (((nt * 24) + (2 * q + w)) * 64 + l) * 8);

  // ---- combine-role constants (one (row,u) pair per thread) ----
  const int row_c = tid >> 3;                  // 0..15
  const int uu    = tid & 7;
  const int b_out = g * 16 + row_c;
  const int u_out = m * 8 + uu;
  float breg[4];
  #pragma unroll
  for (int gg = 0; gg < 4; ++gg) breg[gg] = bias[gg * Uu + u_out];
  float creg = 0.f;

  // ---- load-role constants (lane-level, MFMA A-fragment) ----
  const int b_ld = g * 16 + (l & 15);
  const int kq   = (l >> 4) * 8;
  // wave 0: lane l polls producer (g, l)'s dedicated 64-B tag line
  const u32* tagp = tags + ((size_t)g * 64 + l) * TAGSTRIDE;

  for (int t = 0; t < Tt; ++t) {
    // ---- wave 0 issues the first tag probe early (overlaps x phase) ----
    u32 tv = (u32)t;                             // wave 1: vacuous pass
    if (w == 0)
      asm volatile("global_load_dword %0, %1, off sc1"
                   : "=v"(tv) : "v"(tagp) : "memory");

    // ---- x phase: fp32 loads + cvt + 8 MFMAs (kt = 2q+w) ----
    f32x4 aX0 = {0.f, 0.f, 0.f, 0.f};
    f32x4 aX1 = {0.f, 0.f, 0.f, 0.f};
    const float* xp = x + ((size_t)b_ld * Tt + t) * 256 + kq;
    #pragma unroll
    for (int q = 0; q < 4; ++q) {
      const int kt = 2 * q + w;
      const float4 v0 = *(const float4*)(xp + kt * 32);
      const float4 v1 = *(const float4*)(xp + kt * 32 + 4);
      int r0, r1, r2, r3;
      asm("v_cvt_pk_bf16_f32 %0, %1, %2" : "=v"(r0) : "v"(v0.x), "v"(v0.y));
      asm("v_cvt_pk_bf16_f32 %0, %1, %2" : "=v"(r1) : "v"(v0.z), "v"(v0.w));
      asm("v_cvt_pk_bf16_f32 %0, %1, %2" : "=v"(r2) : "v"(v1.x), "v"(v1.y));
      asm("v_cvt_pk_bf16_f32 %0, %1, %2" : "=v"(r3) : "v"(v1.z), "v"(v1.w));
      const int4v ai = {r0, r1, r2, r3};
      const bf16x8 a = __builtin_bit_cast(bf16x8, ai);
      aX0 = __builtin_amdgcn_mfma_f32_16x16x32_bf16(a, wfx[q][0], aX0, 0, 0, 0);
      aX1 = __builtin_amdgcn_mfma_f32_16x16x32_bf16(a, wfx[q][1], aX1, 0, 0, 0);
    }

    // ---- acquire: wave 0 polls spread tags; wave 1 waits at barrier ----
    asm volatile("s_waitcnt vmcnt(0)" ::: "memory");
    __builtin_amdgcn_sched_barrier(0);
    if (w == 0) {
      while (!__all(tv >= (u32)t)) {
        __builtin_amdgcn_s_sleep(1);
        tv = load_tag_wait(tagp);
        __builtin_amdgcn_sched_barrier(0);
      }
    }
    __builtin_amdgcn_s_barrier();                // hand-off: tags observed
    __builtin_amdgcn_sched_barrier(0);

    // ---- h data loads: issued strictly after the tag pass ----
    const unsigned short* hrow =
        hbuf + ((size_t)(t & 1) * 64 + b_ld) * Uu + kq;
    int4v hf[8];
    #pragma unroll
    for (int q = 0; q < 8; ++q)
      hf[q] = load16_ag(hrow + (2 * q + w) * 32);
    asm volatile("s_waitcnt vmcnt(0)" ::: "memory");
    __builtin_amdgcn_sched_barrier(0);

    // ---- h phase: 16 MFMAs, contiguous fragments ----
    f32x4 aH0 = {0.f, 0.f, 0.f, 0.f};
    f32x4 aH1 = {0.f, 0.f, 0.f, 0.f};
    #pragma unroll
    for (int q = 0; q < 8; ++q) {
      const int kt = 8 + 2 * q + w;
      const bf16x8 a = __builtin_bit_cast(bf16x8, hf[q]);
      const bf16x8 b0 = *(const bf16x8*)(wf + ((0 * 24 + kt) * 64 + l) * 8);
      const bf16x8 b1 = *(const bf16x8*)(wf + ((1 * 24 + kt) * 64 + l) * 8);
      aH0 = __builtin_amdgcn_mfma_f32_16x16x32_bf16(a, b0, aH0, 0, 0, 0);
      aH1 = __builtin_amdgcn_mfma_f32_16x16x32_bf16(a, b1, aH1, 0, 0, 0);
    }

    const f32x4 z0 = aX0 + aH0;
    const f32x4 z1 = aX1 + aH1;

    // ---- cross-wave z reduce through zbuf ----
    __syncthreads();                             // WAR vs previous combine
    {
      float* zb = zbuf + ((w * 2 + 0) * 16 + (l >> 4) * 4) * 17 + (l & 15);
      #pragma unroll
      for (int r = 0; r < 4; ++r) {
        zb[r * 17]           = z0[r];
        zb[r * 17 + 16 * 17] = z1[r];            // nt=1 plane
      }
    }
    __syncthreads();

    // ---- gate math (fp32), cell update ----
    float z[4];
    #pragma unroll
    for (int gg = 0; gg < 4; ++gg) {
      const int n  = gg * 8 + uu;
      const int nt = n >> 4, nc = n & 15;
      z[gg] = zbuf[((0 + nt) * 16 + row_c) * 17 + nc]
            + zbuf[((2 + nt) * 16 + row_c) * 17 + nc]
            + breg[gg];
    }
    const float ig = sigf(z[0]);
    const float fg = sigf(z[1]);
    const float og = sigf(z[3]);
    const float cc = fg * creg + ig * z[2];
    creg = cc;
    const float hh = og * cc;

    // ---- release: h store -> drain -> barrier -> tag store ----
    store2_ag(hbuf + ((size_t)((t + 1) & 1) * 64 + b_out) * Uu + u_out,
              f2bf(hh));
    asm volatile("s_waitcnt vmcnt(0)" ::: "memory");   // h at IF$ NOW
    __builtin_amdgcn_sched_barrier(0);
    __builtin_amdgcn_s_barrier();                // all 128 producers drained
    if (tid == 0)
      store4_ag(tags + ((size_t)g * 64 + m) * TAGSTRIDE, (u32)(t + 1));

    // out store: non-temporal fire-and-forget, off the critical path
    __builtin_nontemporal_store(tanh_fast(hh),
                                &out[((size_t)b_out * Tt + t) * Uu + u_out]);
  }
}

extern "C" void kernel_launch(void* const* d_in, const int* in_sizes, int n_in,
                              void* d_out, int out_size, void* d_ws, size_t ws_size,
                              hipStream_t stream) {
  const float* x    = (const float*)d_in[0];
  const float* Wk   = (const float*)d_in[1];
  const float* Rk   = (const float*)d_in[2];
  const float* bias = (const float*)d_in[3];
  float* out = (float*)d_out;
  unsigned short* hbuf = (unsigned short*)d_ws;
  u32* tags = (u32*)((char*)d_ws + (size_t)2 * 64 * Uu * sizeof(unsigned short));

  // zeroed hbuf = h_0 = 0 (both parities); tags 0 = "h_0 published".
  hipMemsetAsync(d_ws, 0,
                 (size_t)2 * 64 * Uu * sizeof(unsigned short)
                   + (size_t)4 * 64 * TAGSTRIDE * sizeof(u32),
                 stream);

  (void)hipFuncSetAttribute((const void*)lstm_persistent,
                            hipFuncAttributeMaxDynamicSharedMemorySize,
                            SMEM_BYTES);

  hipLaunchKernelGGL(lstm_persistent, dim3(NWG), dim3(NTHR), SMEM_BYTES, stream,
                     x, Wk, Rk, bias, out, hbuf, tags);
}